// Round 20
// baseline (48.307 us; speedup 1.0000x reference)
//
#include <hip/hip_runtime.h>
#include <math.h>

// Siddon forward projection, 128^3 grid over [-1,1]^3, voxel = 1/64.
// r18 structure (u8 image in 4x4x4 bricks = 1 line/brick, 2 MB L2-resident;
// per-group rank-sort of 16 rays -> waves hold 4 similar-length rays; K=16
// chunks/ray; batch-2 depth-3 pipeline; dead steps read line 0) with ONE
// change: PERSISTENT grid-stride blocks (2048 = 8/CU cap) looping over
// 16-ray groups -- removes per-block launch/drain occupancy bubbles.

static constexpr float VOX = 0.015625f;   // 2/128, exact power of two
static constexpr float INV_VOX = 64.0f;
static constexpr int   K = 16;
static constexpr int   NVOX = 128 * 128 * 128;
static constexpr int   IDX_MASK = 0x1FFFFF;   // byte offset < 2 MB
static constexpr int   RPB = 16;              // rays per group
static constexpr int   NBLOCKS = 2048;        // 8 blocks/CU x 256 CUs

struct TState {
  float alx, aly, alz;   // next-crossing alpha per axis
  float dax, day, daz;   // alpha increment per crossing
  float acur, aend;
  int   ix, iy, iz;      // current voxel
  int   stx, sty, stz;   // walk direction
};

// bricked byte address: (bx<<16|by<<11|bz<<6) | (lx<<4|ly<<2|lz)
__device__ __forceinline__ int brick_addr(int ix, int iy, int iz) {
  int hx = ((ix & 0x7C) << 14) | ((ix & 3) << 4);
  int hy = ((iy & 0x7C) << 9)  | ((iy & 3) << 2);
  int hz = ((iz & 0x7C) << 4)  | (iz & 3);
  return (hx | hy | hz) & IDX_MASK;
}

__device__ __forceinline__ void step2(const unsigned char* __restrict__ image,
                                      TState& S, float dif2[2], float v2[2]) {
#pragma unroll
  for (int j = 0; j < 2; ++j) {
    float anext = fminf(fminf(S.alx, S.aly), S.alz);
    float astop = fminf(anext, S.aend);
    float dif   = fmaxf(astop - S.acur, 0.0f);
    dif2[j] = dif;
    // dead/padded steps (dif==0) broadcast-read line 0, not random lines
    int addr = (dif > 0.0f) ? brick_addr(S.ix, S.iy, S.iz) : 0;
    v2[j] = (float)image[addr];
    S.acur = astop;
    bool cx = S.alx <= anext;
    bool cy = S.aly <= anext;
    bool cz = S.alz <= anext;
    S.ix += cx ? S.stx : 0;  S.alx += cx ? S.dax : 0.0f;
    S.iy += cy ? S.sty : 0;  S.aly += cy ? S.day : 0.0f;
    S.iz += cz ? S.stz : 0;  S.alz += cz ? S.daz : 0.0f;
  }
}

// First plane index strictly past astart in walk order, its alpha, the alpha
// increment, the voxel containing astart, and crossing count in (astart,aend].
__device__ __forceinline__ void axis_init(float astart, float aend, float p0,
                                          float ds, float inv,
                                          int& st, int& iv, float& al, float& da,
                                          int& cnt) {
  float ts = (fmaf(astart, ds, p0) + 1.0f) * INV_VOX;
  float te = (fmaf(aend,   ds, p0) + 1.0f) * INV_VOX;
  int ip;
  if (ds > 0.0f) {
    ip = (int)floorf(ts) + 1;
    int il = (int)floorf(te); if (il > 128) il = 128;
    cnt = il - ip + 1; st = 1; iv = ip - 1;
  } else {
    ip = (int)ceilf(ts) - 1;
    int il = (int)ceilf(te); if (il < 0) il = 0;
    cnt = ip - il + 1; st = -1; iv = ip;
  }
  if (cnt < 0) cnt = 0;
  al = (fmaf((float)ip, VOX, -1.0f) - p0) * inv;
  da = VOX * fabsf(inv);
}

__device__ __forceinline__ void ray_setup(const float* L,
    float& p0x, float& p0y, float& p0z,
    float& dx, float& dy, float& dz,
    float& dsx, float& dsy, float& dsz,
    float& invx, float& invy, float& invz,
    float& amin, float& amax) {
  p0x = L[0]; p0y = L[1]; p0z = L[2];
  dx = L[3] - p0x; dy = L[4] - p0y; dz = L[5] - p0z;
  const float eps = 1e-9f;
  dsx = (fabsf(dx) < eps) ? eps : dx;
  dsy = (fabsf(dy) < eps) ? eps : dy;
  dsz = (fabsf(dz) < eps) ? eps : dz;
  invx = __builtin_amdgcn_rcpf(dsx);
  invy = __builtin_amdgcn_rcpf(dsy);
  invz = __builtin_amdgcn_rcpf(dsz);
  float a0 = (-1.0f - p0x) * invx, a1 = (1.0f - p0x) * invx;
  float axmin = fminf(a0, a1), axmax = fmaxf(a0, a1);
  a0 = (-1.0f - p0y) * invy; a1 = (1.0f - p0y) * invy;
  float aymin = fminf(a0, a1), aymax = fmaxf(a0, a1);
  a0 = (-1.0f - p0z) * invz; a1 = (1.0f - p0z) * invz;
  float azmin = fminf(a0, a1), azmax = fmaxf(a0, a1);
  amin = fmaxf(fmaxf(axmin, aymin), fmaxf(azmin, 0.0f));
  amax = fminf(fminf(axmax, aymax), fminf(azmax, 1.0f));
}

// --- image fp32 linear -> u8 bricked -----------------------------------------
__global__ __launch_bounds__(256) void convert_brick(
    const float* __restrict__ img, unsigned char* __restrict__ h)
{
  int i = blockIdx.x * blockDim.x + threadIdx.x;
  int stride = gridDim.x * blockDim.x;
  for (int hi = i; hi < NVOX; hi += stride) {
    int lz = hi & 3, ly = (hi >> 2) & 3, lx = (hi >> 4) & 3;
    int bz = (hi >> 6) & 31, by = (hi >> 11) & 31, bx = (hi >> 16) & 31;
    int ix = (bx << 2) | lx, iy = (by << 2) | ly, iz = (bz << 2) | lz;
    float v = img[(((ix << 7) | iy) << 7) | iz];
    v = fminf(fmaxf(v, 0.0f), 1.0f);
    h[hi] = (unsigned char)(int)rintf(v * 255.0f);
  }
}

// --- traversal: persistent blocks, grid-stride over 16-ray groups ------------
__global__ __launch_bounds__(256) void siddon_fp(
    const unsigned char* __restrict__ image,
    const float* __restrict__ lors,
    float* __restrict__ out, int n)
{
  __shared__ int sV[RPB];
  __shared__ unsigned char sOrd[RPB];

  const int tid = threadIdx.x;
  const int ngroup = (n + RPB - 1) / RPB;

  for (int g = blockIdx.x; g < ngroup; g += gridDim.x) {
    const int rayBase = g * RPB;
    __syncthreads();                    // guard LDS reuse across iterations

    // ---- phase 1: 16 lanes compute per-ray crossing count -------------------
    if (tid < RPB) {
      int ray = rayBase + tid;
      int V = 0;
      if (ray < n) {
        float p0x,p0y,p0z,dx,dy,dz,dsx,dsy,dsz,invx,invy,invz,amin,amax;
        ray_setup(lors + (long)ray * 6, p0x,p0y,p0z, dx,dy,dz,
                  dsx,dsy,dsz, invx,invy,invz, amin,amax);
        if (amax > amin) {
          int st, iv, c0, c1, c2; float al, da;
          axis_init(amin, amax, p0x, dsx, invx, st, iv, al, da, c0);
          axis_init(amin, amax, p0y, dsy, invy, st, iv, al, da, c1);
          axis_init(amin, amax, p0z, dsz, invz, st, iv, al, da, c2);
          V = c0 + c1 + c2 + 1;
        }
      }
      sV[tid] = V;
    }
    __syncthreads();

    // ---- rank-sort 16 rays descending by V (deterministic tie-break) --------
    if (tid < RPB) {
      int v = sV[tid];
      int rank = 0;
#pragma unroll
      for (int j = 0; j < RPB; ++j) {
        int vj = sV[j];
        rank += (vj > v) || (vj == v && j < tid);
      }
      sOrd[rank] = (unsigned char)tid;
    }
    __syncthreads();

    // ---- phase 2: traversal; lane-group q takes sorted ray rank q -----------
    int ray = rayBase + (int)sOrd[tid >> 4];
    int k   = tid & (K - 1);
    bool live = ray < n;

    float acc0 = 0.0f, acc1 = 0.0f;
    if (live) {
      float p0x,p0y,p0z,dx,dy,dz,dsx,dsy,dsz,invx,invy,invz,amin,amax;
      ray_setup(lors + (long)ray * 6, p0x,p0y,p0z, dx,dy,dz,
                dsx,dsy,dsz, invx,invy,invz, amin,amax);

      if (amax > amin) {
        float s      = (amax - amin) * (1.0f / (float)K);
        float astart = fmaf((float)k, s, amin);
        float aend   = (k == K - 1) ? amax : fmaf((float)(k + 1), s, amin);

        TState S;
        S.acur = astart; S.aend = aend;
        int c0, c1, c2;
        axis_init(astart, aend, p0x, dsx, invx, S.stx, S.ix, S.alx, S.dax, c0);
        axis_init(astart, aend, p0y, dsy, invy, S.sty, S.iy, S.aly, S.day, c1);
        axis_init(astart, aend, p0z, dsz, invz, S.stz, S.iz, S.alz, S.daz, c2);

        int ns = c0 + c1 + c2 + 2;      // segments = crossings+1, +1 margin
        int nb = (ns + 1) >> 1;         // batches of 2
        if (nb < 2) nb = 2;             // prologue needs two batches

        float difA[2], difB[2], difC[2];
        float vA[2], vB[2], vC[2];

#define ISSUE(X)   step2(image, S, dif##X, v##X)
#define CONSUME(X)                                                  \
        do { acc0 = fmaf(dif##X[0], v##X[0], acc0);                 \
             acc1 = fmaf(dif##X[1], v##X[1], acc1); } while (0)

        ISSUE(A);
        ISSUE(B);
        int produce = nb - 2;
        while (produce >= 3) {
          ISSUE(C); CONSUME(A);
          ISSUE(A); CONSUME(B);
          ISSUE(B); CONSUME(C);
          produce -= 3;
        }
        if (produce == 2) {
          ISSUE(C); CONSUME(A);
          ISSUE(A); CONSUME(B);
          CONSUME(C); CONSUME(A);
        } else if (produce == 1) {
          ISSUE(C); CONSUME(A);
          CONSUME(B); CONSUME(C);
        } else {
          CONSUME(A); CONSUME(B);
        }
#undef ISSUE
#undef CONSUME

        float rlen = sqrtf(dx * dx + dy * dy + dz * dz);
        acc0 = (acc0 + acc1) * rlen * (1.0f / 255.0f);
        acc1 = 0.0f;
      }
    }

    // reduce the K=16 chunk partials within each 16-lane group
    float acc = acc0 + acc1;
    acc += __shfl_xor(acc, 1);
    acc += __shfl_xor(acc, 2);
    acc += __shfl_xor(acc, 4);
    acc += __shfl_xor(acc, 8);
    if (live && k == 0) out[ray] = acc;
  }
}

extern "C" void kernel_launch(void* const* d_in, const int* in_sizes, int n_in,
                              void* d_out, int out_size, void* d_ws, size_t ws_size,
                              hipStream_t stream) {
  const float* image = (const float*)d_in[0];   // [128,128,128] f32
  const float* lors  = (const float*)d_in[1];   // [N,6] f32
  float* out = (float*)d_out;                   // [N] f32
  int n = out_size;

  unsigned char* h = (unsigned char*)d_ws;      // 2 MB bricked u8 image
  hipLaunchKernelGGL(convert_brick, dim3(2048), dim3(256), 0, stream, image, h);

  int ngroup = (n + RPB - 1) / RPB;
  int grid = ngroup < NBLOCKS ? ngroup : NBLOCKS;
  hipLaunchKernelGGL(siddon_fp, dim3(grid), dim3(256), 0, stream,
                     h, lors, out, n);
}

// Round 21
// 45.763 us; speedup vs baseline: 1.0556x; 1.0556x over previous
//
#include <hip/hip_runtime.h>
#include <math.h>

// Siddon forward projection, 128^3 grid over [-1,1]^3, voxel = 1/64.
// FINAL (r18 revert = measured optimum, 45.9 us total):
// - image as uint8 in 4x4x4 bricks (brick = 64 B = exactly one cache line,
//   2 MB -> fully L2-resident per XCD); reconstruction 1/255 in epilogue
// - 16 rays per 256-thread block; per-block rank-sort by crossing count so
//   each wave holds 4 similar-length rays (miss rays collapse into one wave)
// - K=16 alpha-chunks per ray (one per lane), incremental Siddon step,
//   batch-2 depth-3 software load pipeline, dead steps broadcast line 0
// Floor analysis: ~12M independent lane-gathers at ~2cy/request/CU ~= 40us;
// VALU, line-count, byte-count, balance, depth, occupancy all individually
// probed (r1-r19) -- traversal pinned at 43-48us regardless.

static constexpr float VOX = 0.015625f;   // 2/128, exact power of two
static constexpr float INV_VOX = 64.0f;
static constexpr int   K = 16;
static constexpr int   NVOX = 128 * 128 * 128;
static constexpr int   IDX_MASK = 0x1FFFFF;   // byte offset < 2 MB
static constexpr int   RPB = 16;              // rays per 256-thread block

struct TState {
  float alx, aly, alz;   // next-crossing alpha per axis
  float dax, day, daz;   // alpha increment per crossing
  float acur, aend;
  int   ix, iy, iz;      // current voxel
  int   stx, sty, stz;   // walk direction
};

// bricked byte address: (bx<<16|by<<11|bz<<6) | (lx<<4|ly<<2|lz)
__device__ __forceinline__ int brick_addr(int ix, int iy, int iz) {
  int hx = ((ix & 0x7C) << 14) | ((ix & 3) << 4);
  int hy = ((iy & 0x7C) << 9)  | ((iy & 3) << 2);
  int hz = ((iz & 0x7C) << 4)  | (iz & 3);
  return (hx | hy | hz) & IDX_MASK;
}

__device__ __forceinline__ void step2(const unsigned char* __restrict__ image,
                                      TState& S, float dif2[2], float v2[2]) {
#pragma unroll
  for (int j = 0; j < 2; ++j) {
    float anext = fminf(fminf(S.alx, S.aly), S.alz);
    float astop = fminf(anext, S.aend);
    float dif   = fmaxf(astop - S.acur, 0.0f);
    dif2[j] = dif;
    // dead/padded steps (dif==0) broadcast-read line 0, not random lines
    int addr = (dif > 0.0f) ? brick_addr(S.ix, S.iy, S.iz) : 0;
    v2[j] = (float)image[addr];
    S.acur = astop;
    bool cx = S.alx <= anext;
    bool cy = S.aly <= anext;
    bool cz = S.alz <= anext;
    S.ix += cx ? S.stx : 0;  S.alx += cx ? S.dax : 0.0f;
    S.iy += cy ? S.sty : 0;  S.aly += cy ? S.day : 0.0f;
    S.iz += cz ? S.stz : 0;  S.alz += cz ? S.daz : 0.0f;
  }
}

// First plane index strictly past astart in walk order, its alpha, the alpha
// increment, the voxel containing astart, and crossing count in (astart,aend].
__device__ __forceinline__ void axis_init(float astart, float aend, float p0,
                                          float ds, float inv,
                                          int& st, int& iv, float& al, float& da,
                                          int& cnt) {
  float ts = (fmaf(astart, ds, p0) + 1.0f) * INV_VOX;
  float te = (fmaf(aend,   ds, p0) + 1.0f) * INV_VOX;
  int ip;
  if (ds > 0.0f) {
    ip = (int)floorf(ts) + 1;
    int il = (int)floorf(te); if (il > 128) il = 128;
    cnt = il - ip + 1; st = 1; iv = ip - 1;
  } else {
    ip = (int)ceilf(ts) - 1;
    int il = (int)ceilf(te); if (il < 0) il = 0;
    cnt = ip - il + 1; st = -1; iv = ip;
  }
  if (cnt < 0) cnt = 0;
  al = (fmaf((float)ip, VOX, -1.0f) - p0) * inv;
  da = VOX * fabsf(inv);
}

__device__ __forceinline__ void ray_setup(const float* L,
    float& p0x, float& p0y, float& p0z,
    float& dx, float& dy, float& dz,
    float& dsx, float& dsy, float& dsz,
    float& invx, float& invy, float& invz,
    float& amin, float& amax) {
  p0x = L[0]; p0y = L[1]; p0z = L[2];
  dx = L[3] - p0x; dy = L[4] - p0y; dz = L[5] - p0z;
  const float eps = 1e-9f;
  dsx = (fabsf(dx) < eps) ? eps : dx;
  dsy = (fabsf(dy) < eps) ? eps : dy;
  dsz = (fabsf(dz) < eps) ? eps : dz;
  invx = __builtin_amdgcn_rcpf(dsx);
  invy = __builtin_amdgcn_rcpf(dsy);
  invz = __builtin_amdgcn_rcpf(dsz);
  float a0 = (-1.0f - p0x) * invx, a1 = (1.0f - p0x) * invx;
  float axmin = fminf(a0, a1), axmax = fmaxf(a0, a1);
  a0 = (-1.0f - p0y) * invy; a1 = (1.0f - p0y) * invy;
  float aymin = fminf(a0, a1), aymax = fmaxf(a0, a1);
  a0 = (-1.0f - p0z) * invz; a1 = (1.0f - p0z) * invz;
  float azmin = fminf(a0, a1), azmax = fmaxf(a0, a1);
  amin = fmaxf(fmaxf(axmin, aymin), fmaxf(azmin, 0.0f));
  amax = fminf(fminf(axmax, aymax), fminf(azmax, 1.0f));
}

// --- image fp32 linear -> u8 bricked -----------------------------------------
__global__ __launch_bounds__(256) void convert_brick(
    const float* __restrict__ img, unsigned char* __restrict__ h)
{
  int i = blockIdx.x * blockDim.x + threadIdx.x;
  int stride = gridDim.x * blockDim.x;
  for (int hi = i; hi < NVOX; hi += stride) {
    int lz = hi & 3, ly = (hi >> 2) & 3, lx = (hi >> 4) & 3;
    int bz = (hi >> 6) & 31, by = (hi >> 11) & 31, bx = (hi >> 16) & 31;
    int ix = (bx << 2) | lx, iy = (by << 2) | ly, iz = (bz << 2) | lz;
    float v = img[(((ix << 7) | iy) << 7) | iz];
    v = fminf(fmaxf(v, 0.0f), 1.0f);
    h[hi] = (unsigned char)(int)rintf(v * 255.0f);
  }
}

// --- traversal ---------------------------------------------------------------
__global__ __launch_bounds__(256) void siddon_fp(
    const unsigned char* __restrict__ image,
    const float* __restrict__ lors,
    float* __restrict__ out, int n)
{
  __shared__ int sV[RPB];
  __shared__ unsigned char sOrd[RPB];

  const int tid = threadIdx.x;
  const int rayBase = blockIdx.x * RPB;

  // ---- phase 1: 16 lanes compute per-ray crossing count ---------------------
  if (tid < RPB) {
    int ray = rayBase + tid;
    int V = 0;
    if (ray < n) {
      float p0x,p0y,p0z,dx,dy,dz,dsx,dsy,dsz,invx,invy,invz,amin,amax;
      ray_setup(lors + (long)ray * 6, p0x,p0y,p0z, dx,dy,dz,
                dsx,dsy,dsz, invx,invy,invz, amin,amax);
      if (amax > amin) {
        int st, iv, c0, c1, c2; float al, da;
        axis_init(amin, amax, p0x, dsx, invx, st, iv, al, da, c0);
        axis_init(amin, amax, p0y, dsy, invy, st, iv, al, da, c1);
        axis_init(amin, amax, p0z, dsz, invz, st, iv, al, da, c2);
        V = c0 + c1 + c2 + 1;
      }
    }
    sV[tid] = V;
  }
  __syncthreads();

  // ---- rank-sort 16 rays descending by V (deterministic tie-break) ----------
  if (tid < RPB) {
    int v = sV[tid];
    int rank = 0;
#pragma unroll
    for (int j = 0; j < RPB; ++j) {
      int vj = sV[j];
      rank += (vj > v) || (vj == v && j < tid);
    }
    sOrd[rank] = (unsigned char)tid;
  }
  __syncthreads();

  // ---- phase 2: traversal; lane-group q takes sorted ray rank q -------------
  int ray = rayBase + (int)sOrd[tid >> 4];
  int k   = tid & (K - 1);
  bool live = ray < n;

  float acc0 = 0.0f, acc1 = 0.0f;
  if (live) {
    float p0x,p0y,p0z,dx,dy,dz,dsx,dsy,dsz,invx,invy,invz,amin,amax;
    ray_setup(lors + (long)ray * 6, p0x,p0y,p0z, dx,dy,dz,
              dsx,dsy,dsz, invx,invy,invz, amin,amax);

    if (amax > amin) {
      float s      = (amax - amin) * (1.0f / (float)K);
      float astart = fmaf((float)k, s, amin);
      float aend   = (k == K - 1) ? amax : fmaf((float)(k + 1), s, amin);

      TState S;
      S.acur = astart; S.aend = aend;
      int c0, c1, c2;
      axis_init(astart, aend, p0x, dsx, invx, S.stx, S.ix, S.alx, S.dax, c0);
      axis_init(astart, aend, p0y, dsy, invy, S.sty, S.iy, S.aly, S.day, c1);
      axis_init(astart, aend, p0z, dsz, invz, S.stz, S.iz, S.alz, S.daz, c2);

      int ns = c0 + c1 + c2 + 2;        // segments = crossings+1, +1 margin
      int nb = (ns + 1) >> 1;           // batches of 2
      if (nb < 2) nb = 2;               // prologue needs two batches

      float difA[2], difB[2], difC[2];
      float vA[2], vB[2], vC[2];

#define ISSUE(X)   step2(image, S, dif##X, v##X)
#define CONSUME(X)                                                  \
      do { acc0 = fmaf(dif##X[0], v##X[0], acc0);                   \
           acc1 = fmaf(dif##X[1], v##X[1], acc1); } while (0)

      ISSUE(A);
      ISSUE(B);
      int produce = nb - 2;
      while (produce >= 3) {
        ISSUE(C); CONSUME(A);
        ISSUE(A); CONSUME(B);
        ISSUE(B); CONSUME(C);
        produce -= 3;
      }
      if (produce == 2) {
        ISSUE(C); CONSUME(A);
        ISSUE(A); CONSUME(B);
        CONSUME(C); CONSUME(A);
      } else if (produce == 1) {
        ISSUE(C); CONSUME(A);
        CONSUME(B); CONSUME(C);
      } else {
        CONSUME(A); CONSUME(B);
      }
#undef ISSUE
#undef CONSUME

      float rlen = sqrtf(dx * dx + dy * dy + dz * dz);
      acc0 = (acc0 + acc1) * rlen * (1.0f / 255.0f);
      acc1 = 0.0f;
    }
  }

  // reduce the K=16 chunk partials within each 16-lane group
  float acc = acc0 + acc1;
  acc += __shfl_xor(acc, 1);
  acc += __shfl_xor(acc, 2);
  acc += __shfl_xor(acc, 4);
  acc += __shfl_xor(acc, 8);
  if (live && k == 0) out[ray] = acc;
}

extern "C" void kernel_launch(void* const* d_in, const int* in_sizes, int n_in,
                              void* d_out, int out_size, void* d_ws, size_t ws_size,
                              hipStream_t stream) {
  const float* image = (const float*)d_in[0];   // [128,128,128] f32
  const float* lors  = (const float*)d_in[1];   // [N,6] f32
  float* out = (float*)d_out;                   // [N] f32
  int n = out_size;

  unsigned char* h = (unsigned char*)d_ws;      // 2 MB bricked u8 image
  hipLaunchKernelGGL(convert_brick, dim3(2048), dim3(256), 0, stream, image, h);

  int grid = (n + RPB - 1) / RPB;               // 16 rays per 256-thread block
  hipLaunchKernelGGL(siddon_fp, dim3(grid), dim3(256), 0, stream,
                     h, lors, out, n);
}